// Round 1
// baseline (1193.797 us; speedup 1.0000x reference)
//
#include <hip/hip_runtime.h>
#include <cmath>

constexpr int cBS = 8;
constexpr int cNQ = 1000;
constexpr int cNV = 20000;
constexpr int cE  = 256;
constexpr int cHH = 8;
constexpr int cDH = 32;
constexpr int cP  = 4;
constexpr int cFFN = 512;
constexpr int cH = 100;
constexpr int cW = 200;
constexpr int NTOK = cNQ * cBS;   // 8000

// ---------------------------------------------------------------- elementwise
__global__ __launch_bounds__(256) void k_add2(const float* __restrict__ a,
                                              const float* __restrict__ b,
                                              float* __restrict__ o, int n4)
{
    int i = blockIdx.x * 256 + threadIdx.x;
    if (i < n4) {
        float4 x = reinterpret_cast<const float4*>(a)[i];
        float4 y = reinterpret_cast<const float4*>(b)[i];
        float4 z;
        z.x = x.x + y.x; z.y = x.y + y.y; z.z = x.z + y.z; z.w = x.w + y.w;
        reinterpret_cast<float4*>(o)[i] = z;
    }
}

// ---------------------------------------------------------------- GEMM C = A @ W^T + bias
// A: M x K row-major, W: N x K row-major. 128x128 tile, BK=16, 256 thr, 8x8 micro.
constexpr int GM_PLAIN = 0;
constexpr int GM_RELU  = 1;
constexpr int GM_QKV   = 2;   // writes q/k/v in (BS,HH,NQ,DH), q scaled by 1/sqrt(DH)
constexpr int GM_VPROJ = 3;   // writes (BS,HH,NV,DH)
constexpr int GM_OPROJ = 4;   // rows are (b*NQ+q), writes to (q*BS+b) order

template <int MODE>
__global__ __launch_bounds__(256, 2) void k_gemm(
    const float* __restrict__ A, const float* __restrict__ A2,
    const float* __restrict__ Wm, const float* __restrict__ bias,
    float* __restrict__ C0, float* __restrict__ C1, float* __restrict__ C2,
    int M, int N, int K)
{
    __shared__ float As[16][128];
    __shared__ float Bs[16][128];
    const int t  = threadIdx.x;
    const int n0 = blockIdx.x * 128;
    const int m0 = blockIdx.y * 128;
    const float* Au = (MODE == GM_QKV && n0 >= 2 * cE) ? A2 : A;
    const int lr = t >> 2;          // 0..63
    const int lk = (t & 3) << 2;    // 0,4,8,12
    const int ty = t >> 4;          // 0..15
    const int tx = t & 15;          // 0..15

    float acc[8][8];
#pragma unroll
    for (int i = 0; i < 8; i++)
#pragma unroll
        for (int j = 0; j < 8; j++) acc[i][j] = 0.f;

    for (int k0 = 0; k0 < K; k0 += 16) {
#pragma unroll
        for (int s = 0; s < 2; s++) {
            int row = lr + s * 64;
            int gr  = m0 + row;
            float4 v = make_float4(0.f, 0.f, 0.f, 0.f);
            if (gr < M) v = *reinterpret_cast<const float4*>(&Au[(size_t)gr * K + k0 + lk]);
            As[lk + 0][row] = v.x; As[lk + 1][row] = v.y;
            As[lk + 2][row] = v.z; As[lk + 3][row] = v.w;
            int gn = n0 + row;
            float4 wv = *reinterpret_cast<const float4*>(&Wm[(size_t)gn * K + k0 + lk]);
            Bs[lk + 0][row] = wv.x; Bs[lk + 1][row] = wv.y;
            Bs[lk + 2][row] = wv.z; Bs[lk + 3][row] = wv.w;
        }
        __syncthreads();
#pragma unroll
        for (int kk = 0; kk < 16; kk++) {
            float a[8], b[8];
            *reinterpret_cast<float4*>(&a[0]) = *reinterpret_cast<const float4*>(&As[kk][ty * 8]);
            *reinterpret_cast<float4*>(&a[4]) = *reinterpret_cast<const float4*>(&As[kk][ty * 8 + 4]);
            *reinterpret_cast<float4*>(&b[0]) = *reinterpret_cast<const float4*>(&Bs[kk][tx * 8]);
            *reinterpret_cast<float4*>(&b[4]) = *reinterpret_cast<const float4*>(&Bs[kk][tx * 8 + 4]);
#pragma unroll
            for (int i = 0; i < 8; i++)
#pragma unroll
                for (int j = 0; j < 8; j++) acc[i][j] = fmaf(a[i], b[j], acc[i][j]);
        }
        __syncthreads();
    }

    const int jj = n0 + tx * 8;
    float bv[8];
    *reinterpret_cast<float4*>(&bv[0]) = *reinterpret_cast<const float4*>(&bias[jj]);
    *reinterpret_cast<float4*>(&bv[4]) = *reinterpret_cast<const float4*>(&bias[jj + 4]);
#pragma unroll
    for (int i = 0; i < 8; i++) {
        int gr = m0 + ty * 8 + i;
        if (gr >= M) break;
        float vout[8];
#pragma unroll
        for (int j = 0; j < 8; j++) vout[j] = acc[i][j] + bv[j];
        float* dst;
        if (MODE == GM_PLAIN || MODE == GM_RELU) {
            if (MODE == GM_RELU) {
#pragma unroll
                for (int j = 0; j < 8; j++) vout[j] = fmaxf(vout[j], 0.f);
            }
            dst = C0 + (size_t)gr * N + jj;
        } else if (MODE == GM_QKV) {
            int n = gr >> 3, bb = gr & 7;          // rows are (nq*BS + b)
            int sec = jj >> 8, rem = jj & 255, h = rem >> 5, d0 = rem & 31;
            if (sec == 0) {
#pragma unroll
                for (int j = 0; j < 8; j++) vout[j] *= 0.17677669529663687f; // 1/sqrt(32)
            }
            float* base = (sec == 0) ? C0 : ((sec == 1) ? C1 : C2);
            dst = base + ((size_t)(bb * cHH + h) * cNQ + n) * cDH + d0;
        } else if (MODE == GM_VPROJ) {
            int n = gr >> 3, bb = gr & 7;          // rows are (nv*BS + b)
            int h = jj >> 5, d0 = jj & 31;
            dst = C0 + ((size_t)(bb * cHH + h) * cNV + n) * cDH + d0;
        } else {                                   // GM_OPROJ: rows are (b*NQ+q)
            int bb = gr / cNQ, q = gr - bb * cNQ;
            dst = C0 + ((size_t)q * cBS + bb) * cE + jj;
        }
        *reinterpret_cast<float4*>(dst)     = *reinterpret_cast<float4*>(&vout[0]);
        *reinterpret_cast<float4*>(dst + 4) = *reinterpret_cast<float4*>(&vout[4]);
    }
}

// ---------------------------------------------------------------- attention
// q/k/v: (BS*HH, NQ, DH). out: (NQ, BS, E). One q-row per lane, K split over 4 waves.
__global__ __launch_bounds__(256, 2) void k_attn(
    const float* __restrict__ qh, const float* __restrict__ kh,
    const float* __restrict__ vh, float* __restrict__ outp)
{
    const int bh = blockIdx.x >> 4;     // b*HH + h
    const int qt = blockIdx.x & 15;
    const int t  = threadIdx.x;
    const int r  = t & 63;
    const int w  = t >> 6;
    const int qrow = qt * 64 + r;
    const int qr = (qrow < cNQ) ? qrow : (cNQ - 1);

    const float* qp = qh + ((size_t)bh * cNQ + qr) * cDH;
    float q[32];
#pragma unroll
    for (int i = 0; i < 8; i++) {
        float4 v = *reinterpret_cast<const float4*>(qp + i * 4);
        q[i * 4 + 0] = v.x; q[i * 4 + 1] = v.y; q[i * 4 + 2] = v.z; q[i * 4 + 3] = v.w;
    }
    float o[32];
#pragma unroll
    for (int i = 0; i < 32; i++) o[i] = 0.f;
    float m = -INFINITY, l = 0.f;

    const int kst = w * 250, ken = kst + 250;
    for (int k = kst; k < ken; k++) {
        const float* kr = kh + ((size_t)bh * cNQ + k) * cDH;
        float p0 = 0.f, p1 = 0.f, p2 = 0.f, p3 = 0.f;
#pragma unroll
        for (int i = 0; i < 8; i++) {
            float4 kv = *reinterpret_cast<const float4*>(kr + i * 4);
            float acc = (i & 3) == 0 ? p0 : ((i & 3) == 1 ? p1 : ((i & 3) == 2 ? p2 : p3));
            acc = fmaf(q[i * 4 + 0], kv.x, acc);
            acc = fmaf(q[i * 4 + 1], kv.y, acc);
            acc = fmaf(q[i * 4 + 2], kv.z, acc);
            acc = fmaf(q[i * 4 + 3], kv.w, acc);
            if ((i & 3) == 0) p0 = acc; else if ((i & 3) == 1) p1 = acc;
            else if ((i & 3) == 2) p2 = acc; else p3 = acc;
        }
        float s = (p0 + p1) + (p2 + p3);
        if (s > m) {                 // deferred rescale: rare after warm-up
            float corr = __expf(m - s);
            l *= corr;
#pragma unroll
            for (int i = 0; i < 32; i++) o[i] *= corr;
            m = s;
        }
        float p = __expf(s - m);
        l += p;
        const float* vr = vh + ((size_t)bh * cNQ + k) * cDH;
#pragma unroll
        for (int i = 0; i < 8; i++) {
            float4 vv = *reinterpret_cast<const float4*>(vr + i * 4);
            o[i * 4 + 0] = fmaf(p, vv.x, o[i * 4 + 0]);
            o[i * 4 + 1] = fmaf(p, vv.y, o[i * 4 + 1]);
            o[i * 4 + 2] = fmaf(p, vv.z, o[i * 4 + 2]);
            o[i * 4 + 3] = fmaf(p, vv.w, o[i * 4 + 3]);
        }
    }

    // merge the 4 k-stripes (waves) per q-row
    __shared__ float Lm[4][64];
    __shared__ float Ll[4][64];
    __shared__ float Lo[4][64][33];
    if (w > 0) {
        Lm[w][r] = m; Ll[w][r] = l;
#pragma unroll
        for (int i = 0; i < 32; i++) Lo[w][r][i] = o[i];
    }
    __syncthreads();
    if (w == 0) {
#pragma unroll
        for (int ww = 1; ww < 4; ww++) {
            float m2 = Lm[ww][r], l2 = Ll[ww][r];
            float mn = fmaxf(m, m2);
            float c1 = __expf(m - mn), c2 = __expf(m2 - mn);
            l = l * c1 + l2 * c2;
#pragma unroll
            for (int i = 0; i < 32; i++) o[i] = o[i] * c1 + Lo[ww][r][i] * c2;
            m = mn;
        }
        if (qrow < cNQ) {
            float inv = 1.f / l;
            int bb = bh >> 3, h = bh & 7;
            float* dst = outp + ((size_t)qrow * cBS + bb) * cE + h * cDH;
#pragma unroll
            for (int i = 0; i < 8; i++) {
                float4 vv;
                vv.x = o[i * 4 + 0] * inv; vv.y = o[i * 4 + 1] * inv;
                vv.z = o[i * 4 + 2] * inv; vv.w = o[i * 4 + 3] * inv;
                *reinterpret_cast<float4*>(dst + i * 4) = vv;
            }
        }
    }
}

// ---------------------------------------------------------------- layernorm
// out = LN(a+b)*w + bias ; optional out2 = out + addc
__global__ __launch_bounds__(256) void k_ln(
    const float* __restrict__ a, const float* __restrict__ b,
    const float* __restrict__ w, const float* __restrict__ bias,
    const float* __restrict__ addc,
    float* __restrict__ outp, float* __restrict__ out2)
{
    int rrow = blockIdx.x, t = threadIdx.x;
    size_t base = (size_t)rrow * cE;
    float v = a[base + t] + b[base + t];
    float s = v;
#pragma unroll
    for (int off = 32; off > 0; off >>= 1) s += __shfl_down(s, off, 64);
    __shared__ float red1[4], red2[4];
    int wid = t >> 6, lane = t & 63;
    if (lane == 0) red1[wid] = s;
    __syncthreads();
    float mu = (red1[0] + red1[1] + red1[2] + red1[3]) * (1.f / cE);
    float e = v - mu;
    float s2 = e * e;
#pragma unroll
    for (int off = 32; off > 0; off >>= 1) s2 += __shfl_down(s2, off, 64);
    if (lane == 0) red2[wid] = s2;
    __syncthreads();
    float var = (red2[0] + red2[1] + red2[2] + red2[3]) * (1.f / cE);
    float y = e * (1.f / sqrtf(var + 1e-5f)) * w[t] + bias[t];
    outp[base + t] = y;
    if (out2 != nullptr) out2[base + t] = y + addc[base + t];
}

// ---------------------------------------------------------------- sampling-offset / attn-weight head
// per (b,q): 96 dots of len 256 -> loc (b,q,h,p,2) and softmaxed aw (b,q,h,p)
__global__ __launch_bounds__(128) void k_offaw(
    const float* __restrict__ xq, const float* __restrict__ offw,
    const float* __restrict__ offb, const float* __restrict__ aww,
    const float* __restrict__ awbias, const float* __restrict__ refp,
    float* __restrict__ locO, float* __restrict__ awO)
{
    int bq = blockIdx.x;               // b*NQ + q
    int b = bq / cNQ, q = bq - b * cNQ;
    int t = threadIdx.x;
    __shared__ float row[256];
    __shared__ float raw[96];
    const float* rp = xq + ((size_t)q * cBS + b) * cE;
    row[t] = rp[t];
    row[t + 128] = rp[t + 128];
    __syncthreads();
    if (t < 96) {
        const float* wr; float accb;
        if (t < 64) { wr = offw + (size_t)t * cE;        accb = offb[t]; }
        else        { wr = aww  + (size_t)(t - 64) * cE; accb = awbias[t - 64]; }
        float a0 = 0.f, a1 = 0.f, a2 = 0.f, a3 = 0.f;
        for (int k = 0; k < cE; k += 4) {
            float4 wv = *reinterpret_cast<const float4*>(wr + k);
            a0 = fmaf(row[k + 0], wv.x, a0);
            a1 = fmaf(row[k + 1], wv.y, a1);
            a2 = fmaf(row[k + 2], wv.z, a2);
            a3 = fmaf(row[k + 3], wv.w, a3);
        }
        raw[t] = accb + ((a0 + a1) + (a2 + a3));
    }
    __syncthreads();
    if (t < 64) {                       // t = h*8 + p*2 + c
        int c = t & 1;
        float offv = raw[t];
        float refv = refp[((size_t)b * cNQ + q) * 2 + c];
        float nrm = (c == 0) ? 200.f : 100.f;   // norm = [W, H]
        locO[(size_t)bq * (cHH * cP * 2) + t] = refv + offv / nrm;
    } else if (t < 96) {
        int i = t - 64;                 // h*4 + p
        int h = i >> 2;
        float x0 = raw[64 + h * 4 + 0];
        float x1 = raw[64 + h * 4 + 1];
        float x2 = raw[64 + h * 4 + 2];
        float x3 = raw[64 + h * 4 + 3];
        float mx = fmaxf(fmaxf(x0, x1), fmaxf(x2, x3));
        float e = __expf(raw[t] - mx);
        float ssum = __expf(x0 - mx) + __expf(x1 - mx) + __expf(x2 - mx) + __expf(x3 - mx);
        awO[(size_t)bq * (cHH * cP) + i] = e / ssum;
    }
}

// ---------------------------------------------------------------- MSDA bilinear sample + weight
// thread = (b,q,h,d). vimg: (BS*HH, NV, DH) with NV = H*W. out ms_pre: (b*NQ+q, E)
__device__ __forceinline__ float samp_one(const float* __restrict__ img, int x, int y)
{
    bool ok = (x >= 0) & (x < cW) & (y >= 0) & (y < cH);
    int xc = min(max(x, 0), cW - 1);
    int yc = min(max(y, 0), cH - 1);
    float v = img[(size_t)(yc * cW + xc) * cDH];
    return ok ? v : 0.f;
}

__global__ __launch_bounds__(256) void k_msda(
    const float* __restrict__ vimg, const float* __restrict__ loc,
    const float* __restrict__ aw, float* __restrict__ msp)
{
    int gid = blockIdx.x * 256 + threadIdx.x;   // ((b*NQ+q)*HH + h)*DH + d
    int d  = gid & 31;
    int h  = (gid >> 5) & 7;
    int bq = gid >> 8;
    int b  = bq / cNQ;
    const float* lp = loc + ((size_t)bq * cHH + h) * (cP * 2);
    const float* ap = aw + ((size_t)bq * cHH + h) * cP;
    const float* img = vimg + ((size_t)(b * cHH + h)) * cNV * cDH + d;
    float acc = 0.f;
#pragma unroll
    for (int p = 0; p < cP; p++) {
        float g0 = 2.f * lp[p * 2 + 0] - 1.f;
        float g1 = 2.f * lp[p * 2 + 1] - 1.f;
        float xf = (g0 + 1.f) * 0.5f * (float)cW - 0.5f;
        float yf = (g1 + 1.f) * 0.5f * (float)cH - 0.5f;
        float x0f = floorf(xf), y0f = floorf(yf);
        float wx = xf - x0f, wy = yf - y0f;
        int x0 = (int)x0f, y0 = (int)y0f;
        float v00 = samp_one(img, x0,     y0);
        float v01 = samp_one(img, x0 + 1, y0);
        float v10 = samp_one(img, x0,     y0 + 1);
        float v11 = samp_one(img, x0 + 1, y0 + 1);
        float bil = v00 * (1.f - wx) * (1.f - wy) + v01 * wx * (1.f - wy)
                  + v10 * (1.f - wx) * wy        + v11 * wx * wy;
        acc = fmaf(bil, ap[p], acc);
    }
    msp[gid] = acc;
}

// ---------------------------------------------------------------- launch
extern "C" void kernel_launch(void* const* d_in, const int* in_sizes, int n_in,
                              void* d_out, int out_size, void* d_ws, size_t ws_size,
                              hipStream_t stream)
{
    const float* query = (const float*)d_in[0];
    const float* qpos  = (const float*)d_in[1];
    const float* value = (const float*)d_in[2];
    const float* refp  = (const float*)d_in[3];
    const float* inw   = (const float*)d_in[4];
    const float* inb   = (const float*)d_in[5];
    const float* outw  = (const float*)d_in[6];
    const float* outb  = (const float*)d_in[7];
    const float* ln1w  = (const float*)d_in[8];
    const float* ln1b  = (const float*)d_in[9];
    const float* ln2w  = (const float*)d_in[10];
    const float* ln2b  = (const float*)d_in[11];
    const float* ln3w  = (const float*)d_in[12];
    const float* ln3b  = (const float*)d_in[13];
    const float* offw  = (const float*)d_in[14];
    const float* offb  = (const float*)d_in[15];
    const float* aww   = (const float*)d_in[16];
    const float* awbias= (const float*)d_in[17];
    const float* vpw   = (const float*)d_in[18];
    const float* vpb   = (const float*)d_in[19];
    const float* opw   = (const float*)d_in[20];
    const float* opb   = (const float*)d_in[21];
    const float* f1w   = (const float*)d_in[22];
    const float* f1b   = (const float*)d_in[23];
    const float* f2w   = (const float*)d_in[24];
    const float* f2b   = (const float*)d_in[25];
    float* out = (float*)d_out;

    float* ws = (float*)d_ws;
    const size_t S = (size_t)NTOK * cE;          // 2,048,000 floats
    // workspace map (floats):
    //   slot0..slot3: S each (reused), hbuf: 2*S, loc: 512000, aw: 256000, vimg: 40,960,000
    const size_t need = 6 * S + 512000 + 256000 + (size_t)cBS * cHH * cNV * cDH;
    if (ws_size < need * sizeof(float)) return;  // workspace too small — visible as mismatch

    float* slot0 = ws;
    float* slot1 = ws + S;
    float* slot2 = ws + 2 * S;
    float* slot3 = ws + 3 * S;
    float* hbuf  = ws + 4 * S;
    float* locb  = ws + 6 * S;
    float* awb2  = locb + 512000;
    float* vimg  = awb2 + 256000;

    float* qp  = slot0;
    float* q_h = slot1;
    float* k_h = slot2;
    float* v_h = slot3;

    // qp = query + query_pos
    k_add2<<<dim3((NTOK * cE / 4 + 255) / 256), dim3(256), 0, stream>>>(
        query, qpos, qp, NTOK * cE / 4);

    // value projection -> (BS,HH,NV,DH) image  (independent; issue early)
    k_gemm<GM_VPROJ><<<dim3(2, (cBS * cNV) / 128), dim3(256), 0, stream>>>(
        value, nullptr, vpw, vpb, vimg, nullptr, nullptr, cBS * cNV, cE, cE);

    // QKV projection (q,k from qp; v from query)
    k_gemm<GM_QKV><<<dim3(6, (NTOK + 127) / 128), dim3(256), 0, stream>>>(
        qp, query, inw, inb, q_h, k_h, v_h, NTOK, 3 * cE, cE);

    // attention -> (NQ,BS,E)
    float* attn_pre = slot0;
    k_attn<<<dim3(64 * 16), dim3(256), 0, stream>>>(q_h, k_h, v_h, attn_pre);

    // out-proj
    float* mha_y = slot1;
    k_gemm<GM_PLAIN><<<dim3(2, (NTOK + 127) / 128), dim3(256), 0, stream>>>(
        attn_pre, nullptr, outw, outb, mha_y, nullptr, nullptr, NTOK, cE, cE);

    // LN1: x = LN(query + mha_y), xq = x + query_pos
    float* x  = slot2;
    float* xq = slot3;
    k_ln<<<dim3(NTOK), dim3(256), 0, stream>>>(query, mha_y, ln1w, ln1b, qpos, x, xq);

    // offsets + attention-weights head
    k_offaw<<<dim3(cBS * cNQ), dim3(128), 0, stream>>>(
        xq, offw, offb, aww, awbias, refp, locb, awb2);

    // MSDA bilinear sample
    float* ms_pre = slot0;
    k_msda<<<dim3(NTOK * cE / 256), dim3(256), 0, stream>>>(vimg, locb, awb2, ms_pre);

    // oproj (rows (b,q) -> write (q,b))
    float* ms_y = slot3;
    k_gemm<GM_OPROJ><<<dim3(2, (NTOK + 127) / 128), dim3(256), 0, stream>>>(
        ms_pre, nullptr, opw, opb, ms_y, nullptr, nullptr, NTOK, cE, cE);

    // LN2: x2 = LN(x + ms_y)
    float* x2 = slot1;
    k_ln<<<dim3(NTOK), dim3(256), 0, stream>>>(x, ms_y, ln2w, ln2b, nullptr, x2, nullptr);

    // FFN
    k_gemm<GM_RELU><<<dim3(4, (NTOK + 127) / 128), dim3(256), 0, stream>>>(
        x2, nullptr, f1w, f1b, hbuf, nullptr, nullptr, NTOK, cFFN, cE);
    float* y3 = slot0;
    k_gemm<GM_PLAIN><<<dim3(2, (NTOK + 127) / 128), dim3(256), 0, stream>>>(
        hbuf, nullptr, f2w, f2b, y3, nullptr, nullptr, NTOK, cE, cFFN);

    // LN3 -> out
    k_ln<<<dim3(NTOK), dim3(256), 0, stream>>>(x2, y3, ln3w, ln3b, nullptr, out, nullptr);
}